// Round 1
// baseline (558.045 us; speedup 1.0000x reference)
//
#include <hip/hip_runtime.h>
#include <math.h>

#define BB 16
#define DD 1024
#define TT 4096
#define CD 8
#define CS 1024

// d_out layout (float elements):
//   out      [B][D][T]   @ 0          (67108864)
//   commit   [B]         @ 67108864
//   code     [B]         @ 67108880
//   indices  [B][T]      @ 67108896   (65536, written as float)
//   z_e      [B][CD][T]  @ 67174432   (524288)
#define OFF_LOSS_C 67108864
#define OFF_LOSS_B 67108880
#define OFF_IDX    67108896
#define OFF_ZE     67174432

// ws layout (float elements):
//   w_in_T [D][CD] @ 0       (transposed: ws[d*8+o])
//   w_out  [D][CD] @ 8192
//   cbn    [CS][CD] @ 16384  (fp32 L2-normalized codebook rows)
//   csh    [CS] (double) @ 24576 : 0.5*|c_n|^2 in fp64
#define WS_WIN  0
#define WS_WOUT 8192
#define WS_CBN  16384
#define WS_CS   24576

#define TILE_T 128

// ---------------- prep: 16 blocks, fully parallel (unchanged, proven) ----------------
__global__ __launch_bounds__(256) void prep_kernel(
    const float* __restrict__ in_v,   // [CD][D]
    const float* __restrict__ in_g,   // [CD]
    const float* __restrict__ out_v,  // [D][CD]
    const float* __restrict__ out_g,  // [D]
    const float* __restrict__ cb,     // [CS][CD]
    float* __restrict__ ws)
{
    int bid = blockIdx.x, tid = threadIdx.x;
    if (bid < 8) {
        __shared__ float red[256];
        __shared__ float ssc;
        int o = bid;
        float p = 0.f;
        for (int k = tid; k < DD; k += 256) { float v = in_v[o*DD + k]; p += v*v; }
        red[tid] = p; __syncthreads();
        for (int s = 128; s > 0; s >>= 1) { if (tid < s) red[tid] += red[tid+s]; __syncthreads(); }
        if (tid == 0) ssc = in_g[o] / sqrtf(red[0]);
        __syncthreads();
        float scale = ssc;
        for (int d = tid; d < DD; d += 256)
            ws[WS_WIN + d*CD + o] = in_v[o*DD + d] * scale;
    } else if (bid < 12) {
        int d = (bid - 8) * 256 + tid;
        float v[CD]; float ssq = 0.f;
        #pragma unroll
        for (int c = 0; c < CD; ++c) { v[c] = out_v[d*CD + c]; ssq += v[c]*v[c]; }
        float s = out_g[d] / sqrtf(ssq);
        #pragma unroll
        for (int c = 0; c < CD; ++c) ws[WS_WOUT + d*CD + c] = v[c]*s;
    } else {
        int c = (bid - 12) * 256 + tid;
        double* csh = (double*)(ws + WS_CS);
        float v[CD]; float ssq = 0.f;
        #pragma unroll
        for (int j = 0; j < CD; ++j) { v[j] = cb[c*CD + j]; ssq += v[j]*v[j]; }
        float n = fmaxf(sqrtf(ssq), 1e-12f);
        double sq = 0.0;
        #pragma unroll
        for (int j = 0; j < CD; ++j) {
            float e = v[j] / n;
            ws[WS_CBN + c*CD + j] = e;
            sq = fma((double)e, (double)e, sq);
        }
        csh[c] = 0.5 * sq;
    }
}

// ---------------- fused vq + out_proj: 128 t per block, 512 threads, 512 blocks ----------------
__global__ __launch_bounds__(512, 4) void fused_kernel(
    const float* __restrict__ z,     // [B][D][T]
    const float* __restrict__ in_b,  // [CD]
    const float* __restrict__ cb,    // [CS][CD] raw
    const float* __restrict__ out_b, // [D]
    const float* __restrict__ ws,
    float* __restrict__ outb)
{
    __shared__ float  zpart[8][CD][TILE_T];          // 32 KB
    __shared__ float  ze_s[CD][TILE_T];              // 4 KB
    __shared__ float  nrm_s[TILE_T];                 // 0.5 KB
    __shared__ double best_s[4][TILE_T];             // 4 KB
    __shared__ int    bidx_s[4][TILE_T];             // 2 KB
    __shared__ __align__(16) float zq_s[CD][TILE_T]; // 4 KB

    int tid  = threadIdx.x;
    int b    = blockIdx.y;
    int t0   = blockIdx.x * TILE_T;
    int lane = tid & 63;
    int wv   = __builtin_amdgcn_readfirstlane(tid >> 6);  // wave id 0..7, provably uniform

    // ---- phase A: partial z_e; wave wv covers d in [wv*128, wv*128+128),
    //      each lane owns 2 consecutive t via float2 (8 B/lane, 512 B/instr) ----
    {
        const float* zp = z + ((size_t)(b*DD + wv*128)) * TT + t0 + lane*2;
        const float* w  = ws + WS_WIN + wv*128*CD;           // wave-uniform -> scalar loads
        float2 acc[CD];
        #pragma unroll
        for (int o = 0; o < CD; ++o) acc[o] = make_float2(0.f, 0.f);
        #pragma unroll 8
        for (int j = 0; j < 128; ++j) {
            float2 zv = *(const float2*)(zp + (size_t)j * TT);
            #pragma unroll
            for (int o = 0; o < CD; ++o) {
                float wo = w[j*CD + o];
                acc[o].x = fmaf(wo, zv.x, acc[o].x);
                acc[o].y = fmaf(wo, zv.y, acc[o].y);
            }
        }
        #pragma unroll
        for (int o = 0; o < CD; ++o)
            *(float2*)&zpart[wv][o][lane*2] = acc[o];
    }
    __syncthreads();

    // combine 8 partials + bias; write z_e (each thread handles 2 (o,t) pairs)
    #pragma unroll
    for (int p = tid; p < CD*TILE_T; p += 512) {
        int o = p >> 7, t = p & 127;
        float v = (((zpart[0][o][t] + zpart[1][o][t]) + (zpart[2][o][t] + zpart[3][o][t]))
                 + ((zpart[4][o][t] + zpart[5][o][t]) + (zpart[6][o][t] + zpart[7][o][t])))
                 + in_b[o];
        ze_s[o][t] = v;
        outb[OFF_ZE + ((size_t)(b*CD + o)) * TT + t0 + t] = v;
    }
    __syncthreads();
    if (tid < TILE_T) {
        float ssq = 0.f;
        #pragma unroll
        for (int o = 0; o < CD; ++o) { float vv = ze_s[o][tid]; ssq = fmaf(vv, vv, ssq); }
        nrm_s[tid] = fmaxf(sqrtf(ssq), 1e-12f);
    }
    __syncthreads();

    // ---- phase B: argmax, 4 code-chunks of 256, 4 t per chunk-group (fp64 scoring) ----
    {
        int t  = tid & 127;
        int ck = __builtin_amdgcn_readfirstlane(tid >> 7);   // 0..3, wave-uniform
        float nr = nrm_s[t];
        double en[CD];
        #pragma unroll
        for (int o = 0; o < CD; ++o) en[o] = (double)(ze_s[o][t] / nr);
        const float*  cbn = ws + WS_CBN;
        const double* csh = (const double*)(ws + WS_CS);
        int c0 = ck * 256;
        double best = -1.0e300; int bi = c0;
        for (int c = c0; c < c0 + 256; ++c) {
            float cr[CD];
            *(float4*)&cr[0] = *(const float4*)(cbn + c*CD);
            *(float4*)&cr[4] = *(const float4*)(cbn + c*CD + 4);
            double dot = 0.0;
            #pragma unroll
            for (int o = 0; o < CD; ++o) dot = fma((double)cr[o], en[o], dot);
            double score = dot - csh[c];   // monotone in 2*dot - |c|^2
            if (score > best) { best = score; bi = c; }
        }
        best_s[ck][t] = best; bidx_s[ck][t] = bi;
    }
    __syncthreads();

    // ---- combine chunks, index write, codebook gather, losses ----
    if (tid < TILE_T) {
        int t = tid;
        double best = best_s[0][t]; int bi = bidx_s[0][t];
        #pragma unroll
        for (int k = 1; k < 4; ++k) {
            if (best_s[k][t] > best) { best = best_s[k][t]; bi = bidx_s[k][t]; }
        }
        outb[OFF_IDX + b*TT + t0 + t] = (float)bi;

        float q[CD];
        *(float4*)&q[0] = *(const float4*)(cb + bi*CD);
        *(float4*)&q[4] = *(const float4*)(cb + bi*CD + 4);
        #pragma unroll
        for (int o = 0; o < CD; ++o) zq_s[o][t] = q[o];

        float l = 0.f;
        #pragma unroll
        for (int o = 0; o < CD; ++o) { float d = ze_s[o][t] - q[o]; l = fmaf(d, d, l); }
        #pragma unroll
        for (int off = 32; off > 0; off >>= 1) l += __shfl_down(l, off, 64);
        if (lane == 0) {
            float s = l * (1.0f / (CD * TT));
            atomicAdd(outb + OFF_LOSS_C + b, s);
            atomicAdd(outb + OFF_LOSS_B + b, s);
        }
    }
    __syncthreads();

    // ---- phase C: out_proj, 32 float4 t-groups x 16 d-groups of 64 ----
    {
        int tq = tid & 31;     // t = tq*4 .. tq*4+3
        int dg = tid >> 5;     // 0..15
        float4 qv[CD];
        #pragma unroll
        for (int o = 0; o < CD; ++o) qv[o] = *(const float4*)&zq_s[o][tq*4];

        size_t obase = (size_t)b * DD * TT + t0 + tq*4;
        const float4* wv4 = (const float4*)(ws + WS_WOUT);
        #pragma unroll 4
        for (int i = 0; i < 64; ++i) {
            int d = dg*64 + i;
            float wr[CD];
            *(float4*)&wr[0] = wv4[2*d];
            *(float4*)&wr[4] = wv4[2*d + 1];
            float bbv = out_b[d];
            float4 r = make_float4(bbv, bbv, bbv, bbv);
            #pragma unroll
            for (int o = 0; o < CD; ++o) {
                float wo = wr[o];
                r.x = fmaf(wo, qv[o].x, r.x);
                r.y = fmaf(wo, qv[o].y, r.y);
                r.z = fmaf(wo, qv[o].z, r.z);
                r.w = fmaf(wo, qv[o].w, r.w);
            }
            *(float4*)(outb + obase + (size_t)d * TT) = r;
        }
    }
}

extern "C" void kernel_launch(void* const* d_in, const int* in_sizes, int n_in,
                              void* d_out, int out_size, void* d_ws, size_t ws_size,
                              hipStream_t stream) {
    const float* z     = (const float*)d_in[0];
    const float* in_v  = (const float*)d_in[1];
    const float* in_g  = (const float*)d_in[2];
    const float* in_b  = (const float*)d_in[3];
    const float* out_v = (const float*)d_in[4];
    const float* out_g = (const float*)d_in[5];
    const float* out_b = (const float*)d_in[6];
    const float* cb    = (const float*)d_in[7];
    float* ws  = (float*)d_ws;
    float* out = (float*)d_out;

    // zero the 32 loss accumulators (harness poisons d_out with 0xAA)
    hipMemsetAsync(out + OFF_LOSS_C, 0, 32 * sizeof(float), stream);

    prep_kernel<<<16, 256, 0, stream>>>(in_v, in_g, out_v, out_g, cb, ws);
    fused_kernel<<<dim3(TT/TILE_T, BB), 512, 0, stream>>>(z, in_b, cb, out_b, ws, out);
}

// Round 3
// 546.930 us; speedup vs baseline: 1.0203x; 1.0203x over previous
//
#include <hip/hip_runtime.h>
#include <math.h>

#define BB 16
#define DD 1024
#define TT 4096
#define CD 8
#define CS 1024

// d_out layout (float elements):
//   out      [B][D][T]   @ 0          (67108864)
//   commit   [B]         @ 67108864
//   code     [B]         @ 67108880
//   indices  [B][T]      @ 67108896   (65536, written as float)
//   z_e      [B][CD][T]  @ 67174432   (524288)
#define OFF_LOSS_C 67108864
#define OFF_LOSS_B 67108880
#define OFF_IDX    67108896
#define OFF_ZE     67174432

// ws layout (float elements):
//   w_in_T [D][CD] @ 0       (transposed: ws[d*8+o])
//   w_out  [D][CD] @ 8192
//   cbn    [CS][CD] @ 16384  (fp32 L2-normalized codebook rows)
//   csh    [CS] (double) @ 24576 : 0.5*|c_n|^2 in fp64
#define WS_WIN  0
#define WS_WOUT 8192
#define WS_CBN  16384
#define WS_CS   24576

#define TILE_T 64

typedef float vfloat4 __attribute__((ext_vector_type(4)));

// ---------------- prep: 16 blocks, fully parallel (unchanged, proven) ----------------
__global__ __launch_bounds__(256) void prep_kernel(
    const float* __restrict__ in_v,   // [CD][D]
    const float* __restrict__ in_g,   // [CD]
    const float* __restrict__ out_v,  // [D][CD]
    const float* __restrict__ out_g,  // [D]
    const float* __restrict__ cb,     // [CS][CD]
    float* __restrict__ ws)
{
    int bid = blockIdx.x, tid = threadIdx.x;
    if (bid < 8) {
        __shared__ float red[256];
        __shared__ float ssc;
        int o = bid;
        float p = 0.f;
        for (int k = tid; k < DD; k += 256) { float v = in_v[o*DD + k]; p += v*v; }
        red[tid] = p; __syncthreads();
        for (int s = 128; s > 0; s >>= 1) { if (tid < s) red[tid] += red[tid+s]; __syncthreads(); }
        if (tid == 0) ssc = in_g[o] / sqrtf(red[0]);
        __syncthreads();
        float scale = ssc;
        for (int d = tid; d < DD; d += 256)
            ws[WS_WIN + d*CD + o] = in_v[o*DD + d] * scale;
    } else if (bid < 12) {
        int d = (bid - 8) * 256 + tid;
        float v[CD]; float ssq = 0.f;
        #pragma unroll
        for (int c = 0; c < CD; ++c) { v[c] = out_v[d*CD + c]; ssq += v[c]*v[c]; }
        float s = out_g[d] / sqrtf(ssq);
        #pragma unroll
        for (int c = 0; c < CD; ++c) ws[WS_WOUT + d*CD + c] = v[c]*s;
    } else {
        int c = (bid - 12) * 256 + tid;
        double* csh = (double*)(ws + WS_CS);
        float v[CD]; float ssq = 0.f;
        #pragma unroll
        for (int j = 0; j < CD; ++j) { v[j] = cb[c*CD + j]; ssq += v[j]*v[j]; }
        float n = fmaxf(sqrtf(ssq), 1e-12f);
        double sq = 0.0;
        #pragma unroll
        for (int j = 0; j < CD; ++j) {
            float e = v[j] / n;
            ws[WS_CBN + c*CD + j] = e;
            sq = fma((double)e, (double)e, sq);
        }
        csh[c] = 0.5 * sq;
    }
}

// ---------------- fused vq + out_proj: 64 t per block, 256 threads, 1024 blocks ----------------
__global__ __launch_bounds__(256, 4) void fused_kernel(
    const float* __restrict__ z,     // [B][D][T]
    const float* __restrict__ in_b,  // [CD]
    const float* __restrict__ cb,    // [CS][CD] raw
    const float* __restrict__ out_b, // [D]
    const float* __restrict__ ws,
    float* __restrict__ outb)
{
    __shared__ float  zpart[4][CD][TILE_T];          // 8 KB
    __shared__ float  ze_s[CD][TILE_T];              // 2 KB
    __shared__ float  nrm_s[TILE_T];                 // 256 B
    __shared__ double best_s[4][TILE_T];             // 2 KB
    __shared__ int    bidx_s[4][TILE_T];             // 1 KB
    __shared__ __align__(16) float zq_s[CD][TILE_T]; // 2 KB

    int tid  = threadIdx.x;
    int b    = blockIdx.y;
    int t0   = blockIdx.x * TILE_T;
    int tl   = tid & 63;
    int wv   = __builtin_amdgcn_readfirstlane(tid >> 6);  // wave id 0..3, provably uniform

    // ---- phase A: partial z_e; wave wv covers d in [wv*256, wv*256+256),
    //      lane owns one t column; weights are wave-uniform -> scalar loads ----
    {
        const float* zp = z + ((size_t)(b*DD + wv*256)) * TT + t0 + tl;
        const float* w  = ws + WS_WIN + wv*256*CD;
        float acc[CD];
        #pragma unroll
        for (int o = 0; o < CD; ++o) acc[o] = 0.f;
        #pragma unroll 16
        for (int j = 0; j < 256; ++j) {
            float zv = zp[(size_t)j * TT];
            #pragma unroll
            for (int o = 0; o < CD; ++o) acc[o] = fmaf(w[j*CD + o], zv, acc[o]);
        }
        #pragma unroll
        for (int o = 0; o < CD; ++o) zpart[wv][o][tl] = acc[o];
    }
    __syncthreads();

    // combine 4 partials + bias; write z_e (each thread handles 2 (o,t) pairs)
    #pragma unroll
    for (int p = tid; p < CD*TILE_T; p += 256) {
        int o = p >> 6, t = p & 63;
        float v = in_b[o] + ((zpart[0][o][t] + zpart[1][o][t]) +
                             (zpart[2][o][t] + zpart[3][o][t]));
        ze_s[o][t] = v;
        outb[OFF_ZE + ((size_t)(b*CD + o)) * TT + t0 + t] = v;
    }
    __syncthreads();
    if (tid < TILE_T) {
        float ssq = 0.f;
        #pragma unroll
        for (int o = 0; o < CD; ++o) { float vv = ze_s[o][tid]; ssq = fmaf(vv, vv, ssq); }
        nrm_s[tid] = fmaxf(sqrtf(ssq), 1e-12f);
    }
    __syncthreads();

    // ---- phase B: argmax over 256 codes per wave (fp64 scoring) ----
    {
        int t = tl;
        float nr = nrm_s[t];
        double en[CD];
        #pragma unroll
        for (int o = 0; o < CD; ++o) en[o] = (double)(ze_s[o][t] / nr);
        const float*  cbn = ws + WS_CBN;
        const double* csh = (const double*)(ws + WS_CS);
        int c0 = wv * 256;
        double best = -1.0e300; int bi = c0;
        for (int c = c0; c < c0 + 256; ++c) {
            float cr[CD];
            *(float4*)&cr[0] = *(const float4*)(cbn + c*CD);
            *(float4*)&cr[4] = *(const float4*)(cbn + c*CD + 4);
            double dot = 0.0;
            #pragma unroll
            for (int o = 0; o < CD; ++o) dot = fma((double)cr[o], en[o], dot);
            double score = dot - csh[c];   // monotone in 2*dot - |c|^2
            if (score > best) { best = score; bi = c; }
        }
        best_s[wv][t] = best; bidx_s[wv][t] = bi;
    }
    __syncthreads();

    // ---- combine chunks, index write, codebook gather, losses ----
    if (tid < TILE_T) {
        int t = tid;
        double best = best_s[0][t]; int bi = bidx_s[0][t];
        #pragma unroll
        for (int k = 1; k < 4; ++k) {
            if (best_s[k][t] > best) { best = best_s[k][t]; bi = bidx_s[k][t]; }
        }
        outb[OFF_IDX + b*TT + t0 + t] = (float)bi;

        float q[CD];
        *(float4*)&q[0] = *(const float4*)(cb + bi*CD);
        *(float4*)&q[4] = *(const float4*)(cb + bi*CD + 4);
        #pragma unroll
        for (int o = 0; o < CD; ++o) zq_s[o][t] = q[o];

        float l = 0.f;
        #pragma unroll
        for (int o = 0; o < CD; ++o) { float d = ze_s[o][t] - q[o]; l = fmaf(d, d, l); }
        #pragma unroll
        for (int off = 32; off > 0; off >>= 1) l += __shfl_down(l, off, 64);
        if (tid == 0) {
            float s = l * (1.0f / (CD * TT));
            atomicAdd(outb + OFF_LOSS_C + b, s);
            atomicAdd(outb + OFF_LOSS_B + b, s);
        }
    }
    __syncthreads();

    // ---- phase C: out_proj, 16 float4 t-groups x 16 d-groups of 64; NT stores ----
    {
        int tq = tid & 15;     // t = tq*4 .. tq*4+3
        int dg = tid >> 4;     // 0..15
        float4 qv[CD];
        #pragma unroll
        for (int o = 0; o < CD; ++o) qv[o] = *(const float4*)&zq_s[o][tq*4];

        size_t obase = (size_t)b * DD * TT + t0 + tq*4;
        const float4* wv4 = (const float4*)(ws + WS_WOUT);
        #pragma unroll 4
        for (int i = 0; i < 64; ++i) {
            int d = i*16 + dg;
            float wr[CD];
            *(float4*)&wr[0] = wv4[2*d];
            *(float4*)&wr[4] = wv4[2*d + 1];
            float bbv = out_b[d];
            vfloat4 r = { bbv, bbv, bbv, bbv };
            #pragma unroll
            for (int o = 0; o < CD; ++o) {
                float wo = wr[o];
                r.x = fmaf(wo, qv[o].x, r.x);
                r.y = fmaf(wo, qv[o].y, r.y);
                r.z = fmaf(wo, qv[o].z, r.z);
                r.w = fmaf(wo, qv[o].w, r.w);
            }
            __builtin_nontemporal_store(r, (vfloat4*)(outb + obase + (size_t)d * TT));
        }
    }
}

extern "C" void kernel_launch(void* const* d_in, const int* in_sizes, int n_in,
                              void* d_out, int out_size, void* d_ws, size_t ws_size,
                              hipStream_t stream) {
    const float* z     = (const float*)d_in[0];
    const float* in_v  = (const float*)d_in[1];
    const float* in_g  = (const float*)d_in[2];
    const float* in_b  = (const float*)d_in[3];
    const float* out_v = (const float*)d_in[4];
    const float* out_g = (const float*)d_in[5];
    const float* out_b = (const float*)d_in[6];
    const float* cb    = (const float*)d_in[7];
    float* ws  = (float*)d_ws;
    float* out = (float*)d_out;

    // zero the 32 loss accumulators (harness poisons d_out with 0xAA)
    (void)hipMemsetAsync(out + OFF_LOSS_C, 0, 32 * sizeof(float), stream);

    prep_kernel<<<16, 256, 0, stream>>>(in_v, in_g, out_v, out_g, cb, ws);
    fused_kernel<<<dim3(TT/TILE_T, BB), 256, 0, stream>>>(z, in_b, cb, out_b, ws, out);
}

// Round 5
// 536.329 us; speedup vs baseline: 1.0405x; 1.0198x over previous
//
#include <hip/hip_runtime.h>
#include <math.h>

#define BB 16
#define DD 1024
#define TT 4096
#define CD 8
#define CS 1024

// d_out layout (float elements):
//   out      [B][D][T]   @ 0          (67108864)
//   commit   [B]         @ 67108864
//   code     [B]         @ 67108880
//   indices  [B][T]      @ 67108896   (65536, written as float)
//   z_e      [B][CD][T]  @ 67174432   (524288)
#define OFF_LOSS_C 67108864
#define OFF_LOSS_B 67108880
#define OFF_IDX    67108896
#define OFF_ZE     67174432
// K1 partial z_e scratch: lives at the START of the out region (overwritten by K3).
//   part[b][dc(4)][o(8)][T]  = 16*4*8*4096 floats = 8 MB
#define OFF_PART   0

// ws layout (float elements):
//   w_in_T [D][CD] @ 0       (transposed: ws[d*8+o])
//   w_out  [D][CD] @ 8192
//   cbn    [CS][CD] @ 16384  (fp32 L2-normalized codebook rows)
//   csh    [CS] (double) @ 24576 : 0.5*|c_n|^2 in fp64
#define WS_WIN  0
#define WS_WOUT 8192
#define WS_CBN  16384
#define WS_CS   24576

typedef float vfloat4 __attribute__((ext_vector_type(4)));

// ---------------- prep: 16 blocks, fully parallel (unchanged, proven) ----------------
__global__ __launch_bounds__(256) void prep_kernel(
    const float* __restrict__ in_v,   // [CD][D]
    const float* __restrict__ in_g,   // [CD]
    const float* __restrict__ out_v,  // [D][CD]
    const float* __restrict__ out_g,  // [D]
    const float* __restrict__ cb,     // [CS][CD]
    float* __restrict__ ws)
{
    int bid = blockIdx.x, tid = threadIdx.x;
    if (bid < 8) {
        __shared__ float red[256];
        __shared__ float ssc;
        int o = bid;
        float p = 0.f;
        for (int k = tid; k < DD; k += 256) { float v = in_v[o*DD + k]; p += v*v; }
        red[tid] = p; __syncthreads();
        for (int s = 128; s > 0; s >>= 1) { if (tid < s) red[tid] += red[tid+s]; __syncthreads(); }
        if (tid == 0) ssc = in_g[o] / sqrtf(red[0]);
        __syncthreads();
        float scale = ssc;
        for (int d = tid; d < DD; d += 256)
            ws[WS_WIN + d*CD + o] = in_v[o*DD + d] * scale;
    } else if (bid < 12) {
        int d = (bid - 8) * 256 + tid;
        float v[CD]; float ssq = 0.f;
        #pragma unroll
        for (int c = 0; c < CD; ++c) { v[c] = out_v[d*CD + c]; ssq += v[c]*v[c]; }
        float s = out_g[d] / sqrtf(ssq);
        #pragma unroll
        for (int c = 0; c < CD; ++c) ws[WS_WOUT + d*CD + c] = v[c]*s;
    } else {
        int c = (bid - 12) * 256 + tid;
        double* csh = (double*)(ws + WS_CS);
        float v[CD]; float ssq = 0.f;
        #pragma unroll
        for (int j = 0; j < CD; ++j) { v[j] = cb[c*CD + j]; ssq += v[j]*v[j]; }
        float n = fmaxf(sqrtf(ssq), 1e-12f);
        double sq = 0.0;
        #pragma unroll
        for (int j = 0; j < CD; ++j) {
            float e = v[j] / n;
            ws[WS_CBN + c*CD + j] = e;
            sq = fma((double)e, (double)e, sq);
        }
        csh[c] = 0.5 * sq;
    }
}

// ---------------- K1: z_e partials; 4 waves/block, each wave owns one t-chunk;
//                  1 KB-contiguous z reads per wave-load ----------------
// grid: dim3(4 /*tg*/, 4 /*dc*/, 16 /*b*/) = 256 blocks x 256 threads
__global__ __launch_bounds__(256) void zpart_kernel(
    const float* __restrict__ z,   // [B][D][T]
    const float* __restrict__ ws,
    float* __restrict__ outb)
{
    int tid  = threadIdx.x;
    int lane = tid & 63;
    int wv   = __builtin_amdgcn_readfirstlane(tid >> 6);  // 0..3 -> t-chunk within group
    int tg = blockIdx.x, dc = blockIdx.y, b = blockIdx.z;
    int tc = tg * 4 + wv;
    int t0 = tc * 256;

    const float* zp = z + ((size_t)(b*DD + dc*256)) * TT + t0 + lane*4;
    const float* w  = ws + WS_WIN + dc*256*CD;   // wave-uniform -> scalar loads

    float4 acc[CD];
    #pragma unroll
    for (int o = 0; o < CD; ++o) acc[o] = make_float4(0.f, 0.f, 0.f, 0.f);

    // sequential over 256 d's (EXACT same per-(o,t) summation order as prior rounds)
    #pragma unroll 8
    for (int j = 0; j < 256; ++j) {
        float4 zv = *(const float4*)(zp + (size_t)j * TT);
        #pragma unroll
        for (int o = 0; o < CD; ++o) {
            float wo = w[j*CD + o];
            acc[o].x = fmaf(wo, zv.x, acc[o].x);
            acc[o].y = fmaf(wo, zv.y, acc[o].y);
            acc[o].z = fmaf(wo, zv.z, acc[o].z);
            acc[o].w = fmaf(wo, zv.w, acc[o].w);
        }
    }

    size_t pbase = ((size_t)(b*4 + dc)) * CD * TT + t0 + lane*4;
    #pragma unroll
    for (int o = 0; o < CD; ++o)
        *(float4*)(outb + OFF_PART + pbase + (size_t)o * TT) = acc[o];
}

// ---------------- K2: combine + norm + fp64 argmax + z_e/idx/losses ----------------
// grid: dim3(64 /*tc64*/, 16 /*b*/) x 256 threads
__global__ __launch_bounds__(256) void vq_kernel(
    const float* __restrict__ in_b,  // [CD]
    const float* __restrict__ cb,    // [CS][CD] raw
    const float* __restrict__ ws,
    float* __restrict__ outb)
{
    __shared__ float  ze_s[CD][64];
    __shared__ float  nrm_s[64];
    __shared__ double best_s[4][64];
    __shared__ int    bidx_s[4][64];

    int tid = threadIdx.x;
    int b   = blockIdx.y;
    int t0  = blockIdx.x * 64;
    int tl  = tid & 63;
    int wv  = __builtin_amdgcn_readfirstlane(tid >> 6);

    // combine 4 d-chunk partials + bias; write z_e (same ((0+1)+(2+3)) tree)
    #pragma unroll
    for (int p = tid; p < CD*64; p += 256) {
        int o = p >> 6, t = p & 63;
        size_t pb = (size_t)(b*4) * CD * TT + (size_t)o * TT + t0 + t;
        float v0 = outb[OFF_PART + pb];
        float v1 = outb[OFF_PART + pb + (size_t)CD*TT];
        float v2 = outb[OFF_PART + pb + (size_t)2*CD*TT];
        float v3 = outb[OFF_PART + pb + (size_t)3*CD*TT];
        float v = in_b[o] + ((v0 + v1) + (v2 + v3));
        ze_s[o][t] = v;
        outb[OFF_ZE + ((size_t)(b*CD + o)) * TT + t0 + t] = v;
    }
    __syncthreads();
    if (tid < 64) {
        float ssq = 0.f;
        #pragma unroll
        for (int o = 0; o < CD; ++o) { float vv = ze_s[o][tid]; ssq = fmaf(vv, vv, ssq); }
        nrm_s[tid] = fmaxf(sqrtf(ssq), 1e-12f);
    }
    __syncthreads();

    // argmax over 256 codes per wave (fp64 scoring) — verbatim proven code
    {
        int t = tl;
        float nr = nrm_s[t];
        double en[CD];
        #pragma unroll
        for (int o = 0; o < CD; ++o) en[o] = (double)(ze_s[o][t] / nr);
        const float*  cbn = ws + WS_CBN;
        const double* csh = (const double*)(ws + WS_CS);
        int c0 = wv * 256;
        double best = -1.0e300; int bi = c0;
        for (int c = c0; c < c0 + 256; ++c) {
            float cr[CD];
            *(float4*)&cr[0] = *(const float4*)(cbn + c*CD);
            *(float4*)&cr[4] = *(const float4*)(cbn + c*CD + 4);
            double dot = 0.0;
            #pragma unroll
            for (int o = 0; o < CD; ++o) dot = fma((double)cr[o], en[o], dot);
            double score = dot - csh[c];   // monotone in 2*dot - |c|^2
            if (score > best) { best = score; bi = c; }
        }
        best_s[wv][t] = best; bidx_s[wv][t] = bi;
    }
    __syncthreads();

    if (tid < 64) {
        int t = tid;
        double best = best_s[0][t]; int bi = bidx_s[0][t];
        #pragma unroll
        for (int k = 1; k < 4; ++k) {
            if (best_s[k][t] > best) { best = best_s[k][t]; bi = bidx_s[k][t]; }
        }
        outb[OFF_IDX + b*TT + t0 + t] = (float)bi;

        float q[CD];
        *(float4*)&q[0] = *(const float4*)(cb + bi*CD);
        *(float4*)&q[4] = *(const float4*)(cb + bi*CD + 4);
        float l = 0.f;
        #pragma unroll
        for (int o = 0; o < CD; ++o) { float d = ze_s[o][t] - q[o]; l = fmaf(d, d, l); }
        #pragma unroll
        for (int off = 32; off > 0; off >>= 1) l += __shfl_down(l, off, 64);
        if (tid == 0) {
            float s = l * (1.0f / (CD * TT));
            atomicAdd(outb + OFF_LOSS_C + b, s);
            atomicAdd(outb + OFF_LOSS_B + b, s);
        }
    }
}

// ---------------- K3: out_proj; 1 KB-contiguous NT stores ----------------
// grid: dim3(16 /*tc256*/, 4 /*dch*/, 16 /*b*/) x 256 threads
__global__ __launch_bounds__(256) void out_proj_kernel(
    const float* __restrict__ cb,    // raw codebook
    const float* __restrict__ out_b, // [D]
    const float* __restrict__ ws,
    float* __restrict__ outb)
{
    __shared__ __align__(16) float zq_s[CD][256];   // 8 KB

    int tid = threadIdx.x;
    int tc = blockIdx.x, dch = blockIdx.y, b = blockIdx.z;
    int t0 = tc * 256;

    {
        int bi = (int)outb[OFF_IDX + b*TT + t0 + tid];
        const float4* cr = (const float4*)(cb + bi*CD);
        float4 q0 = cr[0], q1 = cr[1];
        zq_s[0][tid] = q0.x; zq_s[1][tid] = q0.y; zq_s[2][tid] = q0.z; zq_s[3][tid] = q0.w;
        zq_s[4][tid] = q1.x; zq_s[5][tid] = q1.y; zq_s[6][tid] = q1.z; zq_s[7][tid] = q1.w;
    }
    __syncthreads();

    int lane = tid & 63;
    int wv   = tid >> 6;           // 0..3 -> 64 d-rows each
    float4 qv[CD];
    #pragma unroll
    for (int o = 0; o < CD; ++o) qv[o] = *(const float4*)&zq_s[o][lane*4];

    int dbase = dch*256 + wv*64;
    size_t obase = ((size_t)(b*DD + dbase)) * TT + t0 + lane*4;
    const float* wp = ws + WS_WOUT + dbase*CD;   // wave-uniform -> scalar loads
    #pragma unroll 4
    for (int i = 0; i < 64; ++i) {
        float wr[CD];
        *(float4*)&wr[0] = *(const float4*)(wp + i*CD);
        *(float4*)&wr[4] = *(const float4*)(wp + i*CD + 4);
        float bbv = out_b[dbase + i];
        vfloat4 r = { bbv, bbv, bbv, bbv };
        #pragma unroll
        for (int o = 0; o < CD; ++o) {
            float wo = wr[o];
            r.x = fmaf(wo, qv[o].x, r.x);
            r.y = fmaf(wo, qv[o].y, r.y);
            r.z = fmaf(wo, qv[o].z, r.z);
            r.w = fmaf(wo, qv[o].w, r.w);
        }
        __builtin_nontemporal_store(r, (vfloat4*)(outb + obase + (size_t)i * TT));
    }
}

extern "C" void kernel_launch(void* const* d_in, const int* in_sizes, int n_in,
                              void* d_out, int out_size, void* d_ws, size_t ws_size,
                              hipStream_t stream) {
    const float* z     = (const float*)d_in[0];
    const float* in_v  = (const float*)d_in[1];
    const float* in_g  = (const float*)d_in[2];
    const float* in_b  = (const float*)d_in[3];
    const float* out_v = (const float*)d_in[4];
    const float* out_g = (const float*)d_in[5];
    const float* out_b = (const float*)d_in[6];
    const float* cb    = (const float*)d_in[7];
    float* ws  = (float*)d_ws;
    float* out = (float*)d_out;

    // zero the 32 loss accumulators (harness poisons d_out with 0xAA)
    (void)hipMemsetAsync(out + OFF_LOSS_C, 0, 32 * sizeof(float), stream);

    prep_kernel<<<16, 256, 0, stream>>>(in_v, in_g, out_v, out_g, cb, ws);
    zpart_kernel<<<dim3(4, 4, BB), 256, 0, stream>>>(z, ws, out);
    vq_kernel<<<dim3(TT/64, BB), 256, 0, stream>>>(in_b, cb, ws, out);
    out_proj_kernel<<<dim3(16, 4, BB), 256, 0, stream>>>(cb, out_b, ws, out);
}